// Round 13
// baseline (301.240 us; speedup 1.0000x reference)
//
#include <hip/hip_runtime.h>
#include <math.h>

// GCN 2-layer forward, zero global atomics.
// Round-12 A/B: native LDS fp atomics changed NOTHING (75us, same counters).
// agg_split now invariant to TLP, ILP, and atomic impl. Revised theory: the
// 16B feat gathers MISS L2 because the words-read (12.8MB) and pagg-write
// (12.5MB) streams thrash the per-XCD L2 (~3.2MB/XCD streaming vs 4MB cap),
// evicting the 1.6MB gather table; misses then serialize on MSHR-limited
// L3/HBM latency. Fix (single variable): non-temporal hints on ALL streaming
// accesses so L2 is reserved for the gather tables. Gather loads stay cached.
//
//   out = log_softmax( Dinv(A+I)Dinv' relu( Dinv(A+I)Dinv' X W1 + b1 ) W2 + b2 )
// Aggregation commutes with W1 -> both layers aggregate 4-vectors.

#define BLK   256
#define G     512      // binning chunks
#define SH    8        // log2(nodes per bucket)
#define S     256      // nodes per bucket
#define MAXNB 512      // LDS bucket-table capacity (NB = 391)

typedef int   v4i __attribute__((ext_vector_type(4)));
typedef float v4f __attribute__((ext_vector_type(4)));

__device__ __forceinline__ v4i ntload_i4(const int* p) {
    return __builtin_nontemporal_load(reinterpret_cast<const v4i*>(p));
}
__device__ __forceinline__ int ntload_i(const int* p) {
    return __builtin_nontemporal_load(p);
}
__device__ __forceinline__ v4f ntload_f4(const float* p) {
    return __builtin_nontemporal_load(reinterpret_cast<const v4f*>(p));
}
__device__ __forceinline__ void ntstore_f4(float* p, v4f v) {
    __builtin_nontemporal_store(v, reinterpret_cast<v4f*>(p));
}
__device__ __forceinline__ void ntstore_i(int* p, int v) {
    __builtin_nontemporal_store(v, p);
}

// ---- pass A: per-chunk bucket histogram (LDS int atomics, nt streamed) ----
__global__ void __launch_bounds__(BLK) k_binA(const int* __restrict__ dst,
                                              int* __restrict__ gh,
                                              int E, int NB, int chunk) {
    __shared__ int hist[MAXNB];
    int g = blockIdx.x, t = threadIdx.x;
    for (int j = t; j < NB; j += BLK) hist[j] = 0;
    __syncthreads();
    int bs = g * chunk, be = min(bs + chunk, E);
    int bs4 = (bs + 3) & ~3, be4 = be & ~3;
    if (be4 <= bs4) {
        for (int e = bs + t; e < be; e += BLK)
            atomicAdd(&hist[ntload_i(dst + e) >> SH], 1);
    } else {
        if (t < bs4 - bs) atomicAdd(&hist[ntload_i(dst + bs + t) >> SH], 1);
        for (int e = bs4 + 4 * t; e < be4; e += 4 * BLK) {
            v4i d = ntload_i4(dst + e);
            atomicAdd(&hist[d.x >> SH], 1);
            atomicAdd(&hist[d.y >> SH], 1);
            atomicAdd(&hist[d.z >> SH], 1);
            atomicAdd(&hist[d.w >> SH], 1);
        }
        if (t < be - be4) atomicAdd(&hist[ntload_i(dst + be4 + t) >> SH], 1);
    }
    __syncthreads();
    for (int j = t; j < NB; j += BLK) gh[j * G + g] = hist[j];  // [bucket][chunk]
}

// ---- 3-kernel exclusive scan over m = NB*G elements (in place) ----
__global__ void __launch_bounds__(BLK) k_scanA(const int* __restrict__ a,
                                               int* __restrict__ bsum, int m) {
    __shared__ int sh[BLK];
    int i = blockIdx.x * BLK + threadIdx.x;
    sh[threadIdx.x] = (i < m) ? a[i] : 0;
    __syncthreads();
    for (int off = BLK >> 1; off > 0; off >>= 1) {
        if (threadIdx.x < off) sh[threadIdx.x] += sh[threadIdx.x + off];
        __syncthreads();
    }
    if (threadIdx.x == 0) bsum[blockIdx.x] = sh[0];
}

__global__ void __launch_bounds__(1024) k_scanB(const int* __restrict__ bsum,
                                                int* __restrict__ boff, int nb) {
    __shared__ int sh[1024];
    int t = threadIdx.x;
    int v = (t < nb) ? bsum[t] : 0;
    sh[t] = v; __syncthreads();
    for (int off = 1; off < 1024; off <<= 1) {
        int u = (t >= off) ? sh[t - off] : 0;
        __syncthreads();
        sh[t] += u;
        __syncthreads();
    }
    if (t < nb) boff[t] = sh[t] - v;   // exclusive
}

__global__ void __launch_bounds__(BLK) k_scanC(int* __restrict__ a,
                                               const int* __restrict__ boff, int m) {
    __shared__ int sh[BLK];
    int t = threadIdx.x;
    int i = blockIdx.x * BLK + t;
    int v = (i < m) ? a[i] : 0;
    sh[t] = v; __syncthreads();
    for (int off = 1; off < BLK; off <<= 1) {
        int u = (t >= off) ? sh[t - off] : 0;
        __syncthreads();
        sh[t] += u;
        __syncthreads();
    }
    if (i < m) a[i] = sh[t] - v + boff[blockIdx.x];
}

// ---- pass B: scatter packed edges into bucket-contiguous runs ----
// word = src | (dst&255)<<24   (src < 2^24). words STORE stays cached
// (scattered 4B stores need L2 write-combining - Round-5 lesson).
__global__ void __launch_bounds__(BLK) k_binB(const int* __restrict__ src,
                                              const int* __restrict__ dst,
                                              const int* __restrict__ offs,
                                              int* __restrict__ words,
                                              int E, int NB, int chunk) {
    __shared__ int cur[MAXNB];
    int g = blockIdx.x, t = threadIdx.x;
    for (int j = t; j < NB; j += BLK) cur[j] = offs[j * G + g];
    __syncthreads();
    int bs = g * chunk, be = min(bs + chunk, E);
    int bs4 = (bs + 3) & ~3, be4 = be & ~3;
    if (be4 <= bs4) {
        for (int e = bs + t; e < be; e += BLK) {
            int d = ntload_i(dst + e);
            int pos = atomicAdd(&cur[d >> SH], 1);
            words[pos] = ntload_i(src + e) | ((d & (S - 1)) << 24);
        }
    } else {
        if (t < bs4 - bs) {
            int e = bs + t, d = ntload_i(dst + e);
            int pos = atomicAdd(&cur[d >> SH], 1);
            words[pos] = ntload_i(src + e) | ((d & (S - 1)) << 24);
        }
        for (int e = bs4 + 4 * t; e < be4; e += 4 * BLK) {
            v4i d = ntload_i4(dst + e);
            v4i s = ntload_i4(src + e);
            int p0 = atomicAdd(&cur[d.x >> SH], 1);
            int p1 = atomicAdd(&cur[d.y >> SH], 1);
            int p2 = atomicAdd(&cur[d.z >> SH], 1);
            int p3 = atomicAdd(&cur[d.w >> SH], 1);
            words[p0] = s.x | ((d.x & (S - 1)) << 24);
            words[p1] = s.y | ((d.y & (S - 1)) << 24);
            words[p2] = s.z | ((d.z & (S - 1)) << 24);
            words[p3] = s.w | ((d.w & (S - 1)) << 24);
        }
        if (t < be - be4) {
            int e = be4 + t, d = ntload_i(dst + e);
            int pos = atomicAdd(&cur[d >> SH], 1);
            words[pos] = ntload_i(src + e) | ((d & (S - 1)) << 24);
        }
    }
}

// ---- degree: K-way split per bucket, LDS count (nt word stream) ----
__global__ void __launch_bounds__(BLK) k_cnt_split(const int* __restrict__ words,
                                                   const int* __restrict__ offs,
                                                   int* __restrict__ pcnt,
                                                   int E, int NB, int K) {
    __shared__ int cnt[S];
    int b = blockIdx.x / K, k = blockIdx.x % K, t = threadIdx.x;
    cnt[t] = 0;
    __syncthreads();
    int e0 = offs[b * G];
    int e1 = (b + 1 < NB) ? offs[(b + 1) * G] : E;
    long len = e1 - e0;
    int bs = e0 + (int)(len * k / K);
    int be = e0 + (int)(len * (k + 1) / K);
    int bs4 = (bs + 3) & ~3, be4 = be & ~3;
    if (be4 <= bs4) {
        for (int e = bs + t; e < be; e += BLK)
            atomicAdd(&cnt[((unsigned)ntload_i(words + e)) >> 24], 1);
    } else {
        if (t < bs4 - bs) atomicAdd(&cnt[((unsigned)ntload_i(words + bs + t)) >> 24], 1);
        for (int e = bs4 + 4 * t; e < be4; e += 4 * BLK) {
            v4i w = ntload_i4(words + e);
            atomicAdd(&cnt[((unsigned)w.x) >> 24], 1);
            atomicAdd(&cnt[((unsigned)w.y) >> 24], 1);
            atomicAdd(&cnt[((unsigned)w.z) >> 24], 1);
            atomicAdd(&cnt[((unsigned)w.w) >> 24], 1);
        }
        if (t < be - be4) atomicAdd(&cnt[((unsigned)ntload_i(words + be4 + t)) >> 24], 1);
    }
    __syncthreads();
    ntstore_i(&pcnt[(b * K + k) * S + t], cnt[t]);   // coalesced stream
}

// ---- combine degree partials; dinv = rsqrt(deg+1); xd = x*dinv ----
__global__ void __launch_bounds__(BLK) k_cnt_comb(const int* __restrict__ pcnt,
                                                  const float* __restrict__ x,
                                                  float* __restrict__ dinv,
                                                  float* __restrict__ xd,
                                                  int n, int K) {
    int b = blockIdx.x, t = threadIdx.x;
    int node = b * S + t;
    if (node >= n) return;
    int c = 0;
    for (int k = 0; k < K; ++k) c += ntload_i(&pcnt[(b * K + k) * S + t]);
    float di = rsqrtf((float)(c + 1));             // +1 self-loop
    dinv[node] = di;
    v4f xv = ntload_f4(x + (size_t)node * 4);
    v4f o = { xv.x * di, xv.y * di, xv.z * di, xv.w * di };
    ntstore_f4(xd + (size_t)node * 4, o);          // read-cached later on gather
}

// ---- aggregation split: nt word stream + CACHED gathers + LDS f32 atomics ----
__device__ __forceinline__ void agg_one(float* agg, unsigned w, const float4* feat4) {
    int s  = w & 0xFFFFFF;
    int dl = w >> 24;
    float4 v = feat4[s];
    unsafeAtomicAdd(&agg[dl],         v.x);
    unsafeAtomicAdd(&agg[S + dl],     v.y);
    unsafeAtomicAdd(&agg[2 * S + dl], v.z);
    unsafeAtomicAdd(&agg[3 * S + dl], v.w);
}

__global__ void __launch_bounds__(BLK) k_agg_split(const int* __restrict__ words,
                                                   const int* __restrict__ offs,
                                                   const float* __restrict__ feat,
                                                   float* __restrict__ pagg,
                                                   int E, int NB, int K) {
    __shared__ float agg[4 * S];
    int b = blockIdx.x / K, k = blockIdx.x % K, t = threadIdx.x;
    agg[t] = 0.f; agg[S + t] = 0.f; agg[2 * S + t] = 0.f; agg[3 * S + t] = 0.f;
    __syncthreads();
    const float4* feat4 = reinterpret_cast<const float4*>(feat);
    int e0 = offs[b * G];
    int e1 = (b + 1 < NB) ? offs[(b + 1) * G] : E;
    long len = e1 - e0;
    int bs = e0 + (int)(len * k / K);
    int be = e0 + (int)(len * (k + 1) / K);
    int bs4 = (bs + 3) & ~3, be4 = be & ~3;
    if (be4 <= bs4) {
        for (int e = bs + t; e < be; e += BLK)
            agg_one(agg, (unsigned)ntload_i(words + e), feat4);
    } else {
        if (t < bs4 - bs) agg_one(agg, (unsigned)ntload_i(words + bs + t), feat4);
        for (int e = bs4 + 4 * t; e < be4; e += 4 * BLK) {
            v4i wv = ntload_i4(words + e);
            unsigned w0 = wv.x, w1 = wv.y, w2 = wv.z, w3 = wv.w;
            // 4 independent CACHED gathers (want these L2-resident)
            float4 v0 = feat4[w0 & 0xFFFFFF];
            float4 v1 = feat4[w1 & 0xFFFFFF];
            float4 v2 = feat4[w2 & 0xFFFFFF];
            float4 v3 = feat4[w3 & 0xFFFFFF];
            int d0 = w0 >> 24, d1 = w1 >> 24, d2 = w2 >> 24, d3 = w3 >> 24;
            unsafeAtomicAdd(&agg[d0], v0.x);         unsafeAtomicAdd(&agg[S + d0], v0.y);
            unsafeAtomicAdd(&agg[2 * S + d0], v0.z); unsafeAtomicAdd(&agg[3 * S + d0], v0.w);
            unsafeAtomicAdd(&agg[d1], v1.x);         unsafeAtomicAdd(&agg[S + d1], v1.y);
            unsafeAtomicAdd(&agg[2 * S + d1], v1.z); unsafeAtomicAdd(&agg[3 * S + d1], v1.w);
            unsafeAtomicAdd(&agg[d2], v2.x);         unsafeAtomicAdd(&agg[S + d2], v2.y);
            unsafeAtomicAdd(&agg[2 * S + d2], v2.z); unsafeAtomicAdd(&agg[3 * S + d2], v2.w);
            unsafeAtomicAdd(&agg[d3], v3.x);         unsafeAtomicAdd(&agg[S + d3], v3.y);
            unsafeAtomicAdd(&agg[2 * S + d3], v3.z); unsafeAtomicAdd(&agg[3 * S + d3], v3.w);
        }
        if (t < be - be4) agg_one(agg, (unsigned)ntload_i(words + be4 + t), feat4);
    }
    __syncthreads();
    v4f p = { agg[t], agg[S + t], agg[2 * S + t], agg[3 * S + t] };
    ntstore_f4(pagg + ((size_t)(b * K + k) * S + t) * 4, p);   // nt stream
}

// ---- layer-1 combine: sum partials + self + fused 4->16(relu)->4 MLP ----
__global__ void __launch_bounds__(BLK) k_comb1(const float* __restrict__ pagg,
                                               const float* __restrict__ dinv,
                                               const float* __restrict__ xd,
                                               const float* __restrict__ W1,
                                               const float* __restrict__ b1,
                                               const float* __restrict__ W2,
                                               float* __restrict__ g2,
                                               int n, int K) {
    int b = blockIdx.x, t = threadIdx.x;
    int node = b * S + t;
    if (node >= n) return;
    v4f s = ntload_f4(xd + (size_t)node * 4);   // self-loop term (streamed here)
    for (int k = 0; k < K; ++k) {
        v4f p = ntload_f4(pagg + ((size_t)(b * K + k) * S + t) * 4);
        s.x += p.x; s.y += p.y; s.z += p.z; s.w += p.w;
    }
    float di = dinv[node];
    float o0 = 0.f, o1 = 0.f, o2 = 0.f, o3 = 0.f;
#pragma unroll
    for (int j = 0; j < 16; ++j) {
        // W1 [4][16] row-major; wave-uniform -> scalar broadcast
        float h = s.x * W1[j] + s.y * W1[16 + j] + s.z * W1[32 + j] + s.w * W1[48 + j];
        float v = di * h + b1[j];
        v = v > 0.f ? v : 0.f;   // relu
        o0 += v * W2[j * 4 + 0];
        o1 += v * W2[j * 4 + 1];
        o2 += v * W2[j * 4 + 2];
        o3 += v * W2[j * 4 + 3];
    }
    v4f o = { o0 * di, o1 * di, o2 * di, o3 * di };
    ntstore_f4(g2 + (size_t)node * 4, o);       // read-cached later on gather
}

// ---- layer-2 combine: sum partials + self + bias + log_softmax ----
__global__ void __launch_bounds__(BLK) k_comb2(const float* __restrict__ pagg,
                                               const float* __restrict__ dinv,
                                               const float* __restrict__ g2,
                                               const float* __restrict__ b2,
                                               float* __restrict__ out,
                                               int n, int K) {
    int b = blockIdx.x, t = threadIdx.x;
    int node = b * S + t;
    if (node >= n) return;
    v4f s = ntload_f4(g2 + (size_t)node * 4);   // self-loop term
    for (int k = 0; k < K; ++k) {
        v4f p = ntload_f4(pagg + ((size_t)(b * K + k) * S + t) * 4);
        s.x += p.x; s.y += p.y; s.z += p.z; s.w += p.w;
    }
    float di = dinv[node];
    float o0 = di * s.x + b2[0];
    float o1 = di * s.y + b2[1];
    float o2 = di * s.z + b2[2];
    float o3 = di * s.w + b2[3];
    float m = fmaxf(fmaxf(o0, o1), fmaxf(o2, o3));
    float sm = expf(o0 - m) + expf(o1 - m) + expf(o2 - m) + expf(o3 - m);
    float l = m + logf(sm);
    v4f r = { o0 - l, o1 - l, o2 - l, o3 - l };
    ntstore_f4(out + (size_t)node * 4, r);
}

extern "C" void kernel_launch(void* const* d_in, const int* in_sizes, int n_in,
                              void* d_out, int out_size, void* d_ws, size_t ws_size,
                              hipStream_t stream) {
    const float* x  = (const float*)d_in[0];
    const float* W1 = (const float*)d_in[1];
    const float* b1 = (const float*)d_in[2];
    const float* W2 = (const float*)d_in[3];
    const float* b2 = (const float*)d_in[4];
    const int*   ei = (const int*)d_in[5];

    const int n = in_sizes[0] / 4;   // 100000
    const int E = in_sizes[5] / 2;   // 3200000
    const int* src = ei;
    const int* dst = ei + E;

    const int NB    = (n + S - 1) / S;        // 391 buckets
    const int chunk = (E + G - 1) / G;        // 6250 edges/chunk
    const int m     = NB * G;                 // 200192 scan elements
    const int mB    = (m + BLK - 1) / BLK;    // 782 (<= 1024 for scanB)

    // workspace layout (16B-aligned)
    char* ws = (char*)d_ws;
    size_t off = 0;
    int*    words = (int*)   (ws + off); off += (size_t)E * 4;    // 12.8 MB
    int*    offs  = (int*)   (ws + off); off += (size_t)m * 4;    // 800 KB
    float*  xd    = (float*) (ws + off); off += (size_t)n * 16;   // 1.6 MB
    float*  g2    = (float*) (ws + off); off += (size_t)n * 16;   // 1.6 MB
    float*  dinv  = (float*) (ws + off); off += (size_t)n * 4;    // 400 KB
    int*    bsum  = (int*)   (ws + off); off += 4096;
    int*    boff  = (int*)   (ws + off); off += 4096;
    // partial buffer: f32x4 partials for agg; int partials for degree alias it
    float*  pagg  = (float*) (ws + off);
    int*    pcnt  = (int*)   (ws + off);
    size_t base = off;
    int K = 8;
    while (K > 1 && base + (size_t)NB * K * S * 16 > ws_size) K >>= 1;
    float* out = (float*)d_out;

    k_binA     <<<G,      BLK,  0, stream>>>(dst, offs, E, NB, chunk);
    k_scanA    <<<mB,     BLK,  0, stream>>>(offs, bsum, m);
    k_scanB    <<<1,      1024, 0, stream>>>(bsum, boff, mB);
    k_scanC    <<<mB,     BLK,  0, stream>>>(offs, boff, m);
    k_binB     <<<G,      BLK,  0, stream>>>(src, dst, offs, words, E, NB, chunk);
    k_cnt_split<<<NB * K, BLK,  0, stream>>>(words, offs, pcnt, E, NB, K);
    k_cnt_comb <<<NB,     BLK,  0, stream>>>(pcnt, x, dinv, xd, n, K);
    k_agg_split<<<NB * K, BLK,  0, stream>>>(words, offs, xd, pagg, E, NB, K);
    k_comb1    <<<NB,     BLK,  0, stream>>>(pagg, dinv, xd, W1, b1, W2, g2, n, K);
    k_agg_split<<<NB * K, BLK,  0, stream>>>(words, offs, g2, pagg, E, NB, K);
    k_comb2    <<<NB,     BLK,  0, stream>>>(pagg, dinv, g2, b2, out, n, K);
}

// Round 14
// 181.682 us; speedup vs baseline: 1.6581x; 1.6581x over previous
//
#include <hip/hip_runtime.h>
#include <math.h>

// GCN 2-layer forward. Round-13 killed the last cache theory: agg_split is
// invariant to TLP, ILP, atomic impl, and nt hints; FETCH==words stream so
// gathers already cache-hit. Surviving model: LDS atomics are LANE-SERIALIZED
// (~3.6 cyc/lane-atomic): 4/edge = 180K cyc/CU = the 75us. Fix: full dst-sort
// (bucket binning + in-bucket counting sort via rowstart cursors), then both
// layer aggregations are per-node REGISTER reductions with ZERO atomics:
// 4 lanes/node read the node's contiguous srcs2 run, shfl-combine, fused MLP.
//
//   out = log_softmax( Dinv(A+I)Dinv' relu( Dinv(A+I)Dinv' X W1 + b1 ) W2 + b2 )
// Aggregation commutes with W1 -> both layers aggregate 4-vectors.

#define BLK   256
#define G     512      // binning chunks
#define SH    8        // log2(nodes per bucket)
#define S     256      // nodes per bucket
#define MAXNB 512      // LDS bucket-table capacity (NB = 391)
#define KS    8        // cnt split factor

// ---- pass A: per-chunk bucket histogram (LDS int atomics, int4-batched) ----
__global__ void __launch_bounds__(BLK) k_binA(const int* __restrict__ dst,
                                              int* __restrict__ gh,
                                              int E, int NB, int chunk) {
    __shared__ int hist[MAXNB];
    int g = blockIdx.x, t = threadIdx.x;
    for (int j = t; j < NB; j += BLK) hist[j] = 0;
    __syncthreads();
    int bs = g * chunk, be = min(bs + chunk, E);
    int bs4 = (bs + 3) & ~3, be4 = be & ~3;
    if (be4 <= bs4) {
        for (int e = bs + t; e < be; e += BLK)
            atomicAdd(&hist[dst[e] >> SH], 1);
    } else {
        if (t < bs4 - bs) atomicAdd(&hist[dst[bs + t] >> SH], 1);
        for (int e = bs4 + 4 * t; e < be4; e += 4 * BLK) {
            int4 d = *reinterpret_cast<const int4*>(dst + e);
            atomicAdd(&hist[d.x >> SH], 1);
            atomicAdd(&hist[d.y >> SH], 1);
            atomicAdd(&hist[d.z >> SH], 1);
            atomicAdd(&hist[d.w >> SH], 1);
        }
        if (t < be - be4) atomicAdd(&hist[dst[be4 + t] >> SH], 1);
    }
    __syncthreads();
    for (int j = t; j < NB; j += BLK) gh[j * G + g] = hist[j];  // [bucket][chunk]
}

// ---- 3-kernel exclusive scan over m = NB*G elements (in place) ----
__global__ void __launch_bounds__(BLK) k_scanA(const int* __restrict__ a,
                                               int* __restrict__ bsum, int m) {
    __shared__ int sh[BLK];
    int i = blockIdx.x * BLK + threadIdx.x;
    sh[threadIdx.x] = (i < m) ? a[i] : 0;
    __syncthreads();
    for (int off = BLK >> 1; off > 0; off >>= 1) {
        if (threadIdx.x < off) sh[threadIdx.x] += sh[threadIdx.x + off];
        __syncthreads();
    }
    if (threadIdx.x == 0) bsum[blockIdx.x] = sh[0];
}

__global__ void __launch_bounds__(1024) k_scanB(const int* __restrict__ bsum,
                                                int* __restrict__ boff, int nb) {
    __shared__ int sh[1024];
    int t = threadIdx.x;
    int v = (t < nb) ? bsum[t] : 0;
    sh[t] = v; __syncthreads();
    for (int off = 1; off < 1024; off <<= 1) {
        int u = (t >= off) ? sh[t - off] : 0;
        __syncthreads();
        sh[t] += u;
        __syncthreads();
    }
    if (t < nb) boff[t] = sh[t] - v;   // exclusive
}

__global__ void __launch_bounds__(BLK) k_scanC(int* __restrict__ a,
                                               const int* __restrict__ boff, int m) {
    __shared__ int sh[BLK];
    int t = threadIdx.x;
    int i = blockIdx.x * BLK + t;
    int v = (i < m) ? a[i] : 0;
    sh[t] = v; __syncthreads();
    for (int off = 1; off < BLK; off <<= 1) {
        int u = (t >= off) ? sh[t - off] : 0;
        __syncthreads();
        sh[t] += u;
        __syncthreads();
    }
    if (i < m) a[i] = sh[t] - v + boff[blockIdx.x];
}

// ---- pass B: scatter packed edges into bucket-contiguous runs ----
// word = src | (dst&255)<<24   (src < 2^24)
__global__ void __launch_bounds__(BLK) k_binB(const int* __restrict__ src,
                                              const int* __restrict__ dst,
                                              const int* __restrict__ offs,
                                              int* __restrict__ words,
                                              int E, int NB, int chunk) {
    __shared__ int cur[MAXNB];
    int g = blockIdx.x, t = threadIdx.x;
    for (int j = t; j < NB; j += BLK) cur[j] = offs[j * G + g];
    __syncthreads();
    int bs = g * chunk, be = min(bs + chunk, E);
    int bs4 = (bs + 3) & ~3, be4 = be & ~3;
    if (be4 <= bs4) {
        for (int e = bs + t; e < be; e += BLK) {
            int d = dst[e];
            int pos = atomicAdd(&cur[d >> SH], 1);
            words[pos] = src[e] | ((d & (S - 1)) << 24);
        }
    } else {
        if (t < bs4 - bs) {
            int e = bs + t, d = dst[e];
            int pos = atomicAdd(&cur[d >> SH], 1);
            words[pos] = src[e] | ((d & (S - 1)) << 24);
        }
        for (int e = bs4 + 4 * t; e < be4; e += 4 * BLK) {
            int4 d = *reinterpret_cast<const int4*>(dst + e);
            int4 s = *reinterpret_cast<const int4*>(src + e);
            int p0 = atomicAdd(&cur[d.x >> SH], 1);
            int p1 = atomicAdd(&cur[d.y >> SH], 1);
            int p2 = atomicAdd(&cur[d.z >> SH], 1);
            int p3 = atomicAdd(&cur[d.w >> SH], 1);
            words[p0] = s.x | ((d.x & (S - 1)) << 24);
            words[p1] = s.y | ((d.y & (S - 1)) << 24);
            words[p2] = s.z | ((d.z & (S - 1)) << 24);
            words[p3] = s.w | ((d.w & (S - 1)) << 24);
        }
        if (t < be - be4) {
            int e = be4 + t, d = dst[e];
            int pos = atomicAdd(&cur[d >> SH], 1);
            words[pos] = src[e] | ((d & (S - 1)) << 24);
        }
    }
}

// ---- degree: KS-way split per bucket, LDS count (int4-batched) ----
__global__ void __launch_bounds__(BLK) k_cnt_split(const int* __restrict__ words,
                                                   const int* __restrict__ offs,
                                                   int* __restrict__ pcnt,
                                                   int E, int NB) {
    __shared__ int cnt[S];
    int b = blockIdx.x / KS, k = blockIdx.x % KS, t = threadIdx.x;
    cnt[t] = 0;
    __syncthreads();
    int e0 = offs[b * G];
    int e1 = (b + 1 < NB) ? offs[(b + 1) * G] : E;
    long len = e1 - e0;
    int bs = e0 + (int)(len * k / KS);
    int be = e0 + (int)(len * (k + 1) / KS);
    int bs4 = (bs + 3) & ~3, be4 = be & ~3;
    if (be4 <= bs4) {
        for (int e = bs + t; e < be; e += BLK)
            atomicAdd(&cnt[((unsigned)words[e]) >> 24], 1);
    } else {
        if (t < bs4 - bs) atomicAdd(&cnt[((unsigned)words[bs + t]) >> 24], 1);
        for (int e = bs4 + 4 * t; e < be4; e += 4 * BLK) {
            int4 w = *reinterpret_cast<const int4*>(words + e);
            atomicAdd(&cnt[((unsigned)w.x) >> 24], 1);
            atomicAdd(&cnt[((unsigned)w.y) >> 24], 1);
            atomicAdd(&cnt[((unsigned)w.z) >> 24], 1);
            atomicAdd(&cnt[((unsigned)w.w) >> 24], 1);
        }
        if (t < be - be4) atomicAdd(&cnt[((unsigned)words[be4 + t]) >> 24], 1);
    }
    __syncthreads();
    pcnt[(b * KS + k) * S + t] = cnt[t];           // coalesced
}

// ---- combine counts; per-bucket scan -> rowstart; dinv; xd = x*dinv ----
__global__ void __launch_bounds__(BLK) k_cnt_comb(const int* __restrict__ pcnt,
                                                  const int* __restrict__ offs,
                                                  const float* __restrict__ x,
                                                  int* __restrict__ rowstart,
                                                  int* __restrict__ cntv,
                                                  float* __restrict__ dinv,
                                                  float* __restrict__ xd,
                                                  int n, int NB) {
    __shared__ int sc[S];
    int b = blockIdx.x, t = threadIdx.x;
    int c = 0;
    for (int k = 0; k < KS; ++k) c += pcnt[(b * KS + k) * S + t];
    sc[t] = c; __syncthreads();
    for (int off = 1; off < S; off <<= 1) {
        int u = (t >= off) ? sc[t - off] : 0;
        __syncthreads();
        sc[t] += u;
        __syncthreads();
    }
    int node = b * S + t;
    rowstart[node] = offs[b * G] + sc[t] - c;      // global CSR row start
    cntv[node] = c;
    if (node < n) {
        float di = rsqrtf((float)(c + 1));         // +1 self-loop
        dinv[node] = di;
        float4 xv = reinterpret_cast<const float4*>(x)[node];
        float4 o = { xv.x * di, xv.y * di, xv.z * di, xv.w * di };
        reinterpret_cast<float4*>(xd)[node] = o;
    }
}

// ---- counting-sort scatter: srcs2[rowstart-cursor] = src, sorted by dst ----
__global__ void __launch_bounds__(BLK) k_sort(const int* __restrict__ words,
                                              const int* __restrict__ offs,
                                              const int* __restrict__ rowstart,
                                              int* __restrict__ srcs2,
                                              int E, int NB) {
    __shared__ int cur[S];
    int b = blockIdx.x, t = threadIdx.x;
    cur[t] = rowstart[b * S + t];                  // absolute cursors
    __syncthreads();
    int e0 = offs[b * G];
    int e1 = (b + 1 < NB) ? offs[(b + 1) * G] : E;
    int bs4 = (e0 + 3) & ~3, be4 = e1 & ~3;
    if (be4 <= bs4) {
        for (int e = e0 + t; e < e1; e += BLK) {
            unsigned w = (unsigned)words[e];
            int pos = atomicAdd(&cur[w >> 24], 1);
            srcs2[pos] = w & 0xFFFFFF;
        }
    } else {
        if (t < bs4 - e0) {
            unsigned w = (unsigned)words[e0 + t];
            int pos = atomicAdd(&cur[w >> 24], 1);
            srcs2[pos] = w & 0xFFFFFF;
        }
        for (int e = bs4 + 4 * t; e < be4; e += 4 * BLK) {
            int4 wv = *reinterpret_cast<const int4*>(words + e);
            unsigned w0 = wv.x, w1 = wv.y, w2 = wv.z, w3 = wv.w;
            int p0 = atomicAdd(&cur[w0 >> 24], 1);
            int p1 = atomicAdd(&cur[w1 >> 24], 1);
            int p2 = atomicAdd(&cur[w2 >> 24], 1);
            int p3 = atomicAdd(&cur[w3 >> 24], 1);
            srcs2[p0] = w0 & 0xFFFFFF;
            srcs2[p1] = w1 & 0xFFFFFF;
            srcs2[p2] = w2 & 0xFFFFFF;
            srcs2[p3] = w3 & 0xFFFFFF;
        }
        if (t < e1 - be4) {
            unsigned w = (unsigned)words[be4 + t];
            int pos = atomicAdd(&cur[w >> 24], 1);
            srcs2[pos] = w & 0xFFFFFF;
        }
    }
}

// ---- layer-1: 4 lanes/node register gather-reduce + shfl + fused MLP ----
__global__ void __launch_bounds__(BLK) k_g1(const int* __restrict__ srcs2,
                                            const int* __restrict__ rowstart,
                                            const int* __restrict__ cntv,
                                            const float* __restrict__ dinv,
                                            const float* __restrict__ xd,
                                            const float* __restrict__ W1,
                                            const float* __restrict__ b1,
                                            const float* __restrict__ W2,
                                            float* __restrict__ g2, int n) {
    int gt = blockIdx.x * BLK + threadIdx.x;
    int node = gt >> 2, g = gt & 3;
    if (node >= n) return;
    int rs = rowstart[node], c = cntv[node];
    const float4* feat4 = reinterpret_cast<const float4*>(xd);
    float sx = 0.f, sy = 0.f, sz = 0.f, sw = 0.f;
    int j = g;
    for (; j + 4 < c; j += 8) {                    // 2-way unrolled, stride 4
        int s0 = srcs2[rs + j];
        int s1 = srcs2[rs + j + 4];
        float4 v0 = feat4[s0];
        float4 v1 = feat4[s1];
        sx += v0.x + v1.x; sy += v0.y + v1.y;
        sz += v0.z + v1.z; sw += v0.w + v1.w;
    }
    if (j < c) {
        float4 v = feat4[srcs2[rs + j]];
        sx += v.x; sy += v.y; sz += v.z; sw += v.w;
    }
    // combine the 4 lanes (no atomics, no LDS)
    sx += __shfl_xor(sx, 1); sx += __shfl_xor(sx, 2);
    sy += __shfl_xor(sy, 1); sy += __shfl_xor(sy, 2);
    sz += __shfl_xor(sz, 1); sz += __shfl_xor(sz, 2);
    sw += __shfl_xor(sw, 1); sw += __shfl_xor(sw, 2);
    float4 xv = feat4[node];                       // self-loop term
    sx += xv.x; sy += xv.y; sz += xv.z; sw += xv.w;
    float di = dinv[node];
    float o0 = 0.f, o1 = 0.f, o2 = 0.f, o3 = 0.f;
#pragma unroll
    for (int jj = 0; jj < 16; ++jj) {
        // W1 [4][16] row-major; wave-uniform -> scalar broadcast
        float h = sx * W1[jj] + sy * W1[16 + jj] + sz * W1[32 + jj] + sw * W1[48 + jj];
        float v = di * h + b1[jj];
        v = v > 0.f ? v : 0.f;   // relu
        o0 += v * W2[jj * 4 + 0];
        o1 += v * W2[jj * 4 + 1];
        o2 += v * W2[jj * 4 + 2];
        o3 += v * W2[jj * 4 + 3];
    }
    if (g == 0) {
        float4 o = { o0 * di, o1 * di, o2 * di, o3 * di };
        reinterpret_cast<float4*>(g2)[node] = o;
    }
}

// ---- layer-2: same structure + bias + log_softmax ----
__global__ void __launch_bounds__(BLK) k_g2(const int* __restrict__ srcs2,
                                            const int* __restrict__ rowstart,
                                            const int* __restrict__ cntv,
                                            const float* __restrict__ dinv,
                                            const float* __restrict__ g2v,
                                            const float* __restrict__ b2,
                                            float* __restrict__ out, int n) {
    int gt = blockIdx.x * BLK + threadIdx.x;
    int node = gt >> 2, g = gt & 3;
    if (node >= n) return;
    int rs = rowstart[node], c = cntv[node];
    const float4* feat4 = reinterpret_cast<const float4*>(g2v);
    float sx = 0.f, sy = 0.f, sz = 0.f, sw = 0.f;
    int j = g;
    for (; j + 4 < c; j += 8) {
        int s0 = srcs2[rs + j];
        int s1 = srcs2[rs + j + 4];
        float4 v0 = feat4[s0];
        float4 v1 = feat4[s1];
        sx += v0.x + v1.x; sy += v0.y + v1.y;
        sz += v0.z + v1.z; sw += v0.w + v1.w;
    }
    if (j < c) {
        float4 v = feat4[srcs2[rs + j]];
        sx += v.x; sy += v.y; sz += v.z; sw += v.w;
    }
    sx += __shfl_xor(sx, 1); sx += __shfl_xor(sx, 2);
    sy += __shfl_xor(sy, 1); sy += __shfl_xor(sy, 2);
    sz += __shfl_xor(sz, 1); sz += __shfl_xor(sz, 2);
    sw += __shfl_xor(sw, 1); sw += __shfl_xor(sw, 2);
    float4 gv = feat4[node];                       // self-loop term
    sx += gv.x; sy += gv.y; sz += gv.z; sw += gv.w;
    float di = dinv[node];
    float o0 = di * sx + b2[0];
    float o1 = di * sy + b2[1];
    float o2 = di * sz + b2[2];
    float o3 = di * sw + b2[3];
    float m = fmaxf(fmaxf(o0, o1), fmaxf(o2, o3));
    float sm = expf(o0 - m) + expf(o1 - m) + expf(o2 - m) + expf(o3 - m);
    float l = m + logf(sm);
    if (g == 0) {
        float4 r = { o0 - l, o1 - l, o2 - l, o3 - l };
        reinterpret_cast<float4*>(out)[node] = r;
    }
}

extern "C" void kernel_launch(void* const* d_in, const int* in_sizes, int n_in,
                              void* d_out, int out_size, void* d_ws, size_t ws_size,
                              hipStream_t stream) {
    const float* x  = (const float*)d_in[0];
    const float* W1 = (const float*)d_in[1];
    const float* b1 = (const float*)d_in[2];
    const float* W2 = (const float*)d_in[3];
    const float* b2 = (const float*)d_in[4];
    const int*   ei = (const int*)d_in[5];

    const int n = in_sizes[0] / 4;   // 100000
    const int E = in_sizes[5] / 2;   // 3200000
    const int* src = ei;
    const int* dst = ei + E;

    const int NB    = (n + S - 1) / S;        // 391 buckets
    const int chunk = (E + G - 1) / G;        // 6250 edges/chunk
    const int m     = NB * G;                 // 200192 scan elements
    const int mB    = (m + BLK - 1) / BLK;    // 782 (<= 1024 for scanB)
    const int NS    = NB * S;                 // 100096 padded nodes

    // workspace (16B-aligned, ~31 MB). pcnt (3.2MB) aliases srcs2 (12.8MB):
    // pcnt is consumed by k_cnt_comb before k_sort writes srcs2.
    char* ws = (char*)d_ws;
    size_t off = 0;
    int*   words    = (int*)  (ws + off); off += (size_t)E * 4;     // 12.8 MB
    int*   srcs2    = (int*)  (ws + off); off += (size_t)E * 4;     // 12.8 MB
    int*   pcnt     = srcs2;                                        // alias
    int*   offs     = (int*)  (ws + off); off += (size_t)m * 4;     // 800 KB
    float* xd       = (float*)(ws + off); off += (size_t)n * 16;    // 1.6 MB
    float* g2       = (float*)(ws + off); off += (size_t)n * 16;    // 1.6 MB
    float* dinv     = (float*)(ws + off); off += (size_t)NS * 4;    // 400 KB
    int*   rowstart = (int*)  (ws + off); off += (size_t)NS * 4;    // 400 KB
    int*   cntv     = (int*)  (ws + off); off += (size_t)NS * 4;    // 400 KB
    int*   bsum     = (int*)  (ws + off); off += 4096;
    int*   boff     = (int*)  (ws + off); off += 4096;
    float* out      = (float*)d_out;

    const int gB = (4 * n + BLK - 1) / BLK;   // 1563 blocks for k_g1/k_g2

    k_binA     <<<G,       BLK,  0, stream>>>(dst, offs, E, NB, chunk);
    k_scanA    <<<mB,      BLK,  0, stream>>>(offs, bsum, m);
    k_scanB    <<<1,       1024, 0, stream>>>(bsum, boff, mB);
    k_scanC    <<<mB,      BLK,  0, stream>>>(offs, boff, m);
    k_binB     <<<G,       BLK,  0, stream>>>(src, dst, offs, words, E, NB, chunk);
    k_cnt_split<<<NB * KS, BLK,  0, stream>>>(words, offs, pcnt, E, NB);
    k_cnt_comb <<<NB,      BLK,  0, stream>>>(pcnt, offs, x, rowstart, cntv, dinv, xd, n, NB);
    k_sort     <<<NB,      BLK,  0, stream>>>(words, offs, rowstart, srcs2, E, NB);
    k_g1       <<<gB,      BLK,  0, stream>>>(srcs2, rowstart, cntv, dinv, xd, W1, b1, W2, g2, n);
    k_g2       <<<gB,      BLK,  0, stream>>>(srcs2, rowstart, cntv, dinv, g2, b2, out, n);
}

// Round 16
// 176.085 us; speedup vs baseline: 1.7108x; 1.0318x over previous
//
#include <hip/hip_runtime.h>
#include <math.h>

// GCN 2-layer forward. R14 confirmed: LDS atomics are lane-serialized; sorted
// register-reduce aggregation (zero atomics) runs at ~15us/layer. Remaining
// cost is the CSR build prefix (~135us). R15: merge cnt_split+cnt_comb+sort
// into ONE per-bucket kernel k_build (histogram -> LDS scan -> node meta ->
// cursor scatter); bucket's words slice is L2-hot for the re-read. 10->8
// dispatches, one fewer 12.8MB cold pass, no pcnt round-trip.
//
//   out = log_softmax( Dinv(A+I)Dinv' relu( Dinv(A+I)Dinv' X W1 + b1 ) W2 + b2 )
// Aggregation commutes with W1 -> both layers aggregate 4-vectors.

#define BLK   256
#define G     512      // binning chunks
#define SH    8        // log2(nodes per bucket)
#define S     256      // nodes per bucket
#define MAXNB 512      // LDS bucket-table capacity (NB = 391)

// ---- pass A: per-chunk bucket histogram (LDS int atomics, int4-batched) ----
__global__ void __launch_bounds__(BLK) k_binA(const int* __restrict__ dst,
                                              int* __restrict__ gh,
                                              int E, int NB, int chunk) {
    __shared__ int hist[MAXNB];
    int g = blockIdx.x, t = threadIdx.x;
    for (int j = t; j < NB; j += BLK) hist[j] = 0;
    __syncthreads();
    int bs = g * chunk, be = min(bs + chunk, E);
    int bs4 = (bs + 3) & ~3, be4 = be & ~3;
    if (be4 <= bs4) {
        for (int e = bs + t; e < be; e += BLK)
            atomicAdd(&hist[dst[e] >> SH], 1);
    } else {
        if (t < bs4 - bs) atomicAdd(&hist[dst[bs + t] >> SH], 1);
        for (int e = bs4 + 4 * t; e < be4; e += 4 * BLK) {
            int4 d = *reinterpret_cast<const int4*>(dst + e);
            atomicAdd(&hist[d.x >> SH], 1);
            atomicAdd(&hist[d.y >> SH], 1);
            atomicAdd(&hist[d.z >> SH], 1);
            atomicAdd(&hist[d.w >> SH], 1);
        }
        if (t < be - be4) atomicAdd(&hist[dst[be4 + t] >> SH], 1);
    }
    __syncthreads();
    for (int j = t; j < NB; j += BLK) gh[j * G + g] = hist[j];  // [bucket][chunk]
}

// ---- 3-kernel exclusive scan over m = NB*G elements (in place) ----
__global__ void __launch_bounds__(BLK) k_scanA(const int* __restrict__ a,
                                               int* __restrict__ bsum, int m) {
    __shared__ int sh[BLK];
    int i = blockIdx.x * BLK + threadIdx.x;
    sh[threadIdx.x] = (i < m) ? a[i] : 0;
    __syncthreads();
    for (int off = BLK >> 1; off > 0; off >>= 1) {
        if (threadIdx.x < off) sh[threadIdx.x] += sh[threadIdx.x + off];
        __syncthreads();
    }
    if (threadIdx.x == 0) bsum[blockIdx.x] = sh[0];
}

__global__ void __launch_bounds__(1024) k_scanB(const int* __restrict__ bsum,
                                                int* __restrict__ boff, int nb) {
    __shared__ int sh[1024];
    int t = threadIdx.x;
    int v = (t < nb) ? bsum[t] : 0;
    sh[t] = v; __syncthreads();
    for (int off = 1; off < 1024; off <<= 1) {
        int u = (t >= off) ? sh[t - off] : 0;
        __syncthreads();
        sh[t] += u;
        __syncthreads();
    }
    if (t < nb) boff[t] = sh[t] - v;   // exclusive
}

__global__ void __launch_bounds__(BLK) k_scanC(int* __restrict__ a,
                                               const int* __restrict__ boff, int m) {
    __shared__ int sh[BLK];
    int t = threadIdx.x;
    int i = blockIdx.x * BLK + t;
    int v = (i < m) ? a[i] : 0;
    sh[t] = v; __syncthreads();
    for (int off = 1; off < BLK; off <<= 1) {
        int u = (t >= off) ? sh[t - off] : 0;
        __syncthreads();
        sh[t] += u;
        __syncthreads();
    }
    if (i < m) a[i] = sh[t] - v + boff[blockIdx.x];
}

// ---- pass B: scatter packed edges into bucket-contiguous runs ----
// word = src | (dst&255)<<24   (src < 2^24)
__global__ void __launch_bounds__(BLK) k_binB(const int* __restrict__ src,
                                              const int* __restrict__ dst,
                                              const int* __restrict__ offs,
                                              int* __restrict__ words,
                                              int E, int NB, int chunk) {
    __shared__ int cur[MAXNB];
    int g = blockIdx.x, t = threadIdx.x;
    for (int j = t; j < NB; j += BLK) cur[j] = offs[j * G + g];
    __syncthreads();
    int bs = g * chunk, be = min(bs + chunk, E);
    int bs4 = (bs + 3) & ~3, be4 = be & ~3;
    if (be4 <= bs4) {
        for (int e = bs + t; e < be; e += BLK) {
            int d = dst[e];
            int pos = atomicAdd(&cur[d >> SH], 1);
            words[pos] = src[e] | ((d & (S - 1)) << 24);
        }
    } else {
        if (t < bs4 - bs) {
            int e = bs + t, d = dst[e];
            int pos = atomicAdd(&cur[d >> SH], 1);
            words[pos] = src[e] | ((d & (S - 1)) << 24);
        }
        for (int e = bs4 + 4 * t; e < be4; e += 4 * BLK) {
            int4 d = *reinterpret_cast<const int4*>(dst + e);
            int4 s = *reinterpret_cast<const int4*>(src + e);
            int p0 = atomicAdd(&cur[d.x >> SH], 1);
            int p1 = atomicAdd(&cur[d.y >> SH], 1);
            int p2 = atomicAdd(&cur[d.z >> SH], 1);
            int p3 = atomicAdd(&cur[d.w >> SH], 1);
            words[p0] = s.x | ((d.x & (S - 1)) << 24);
            words[p1] = s.y | ((d.y & (S - 1)) << 24);
            words[p2] = s.z | ((d.z & (S - 1)) << 24);
            words[p3] = s.w | ((d.w & (S - 1)) << 24);
        }
        if (t < be - be4) {
            int e = be4 + t, d = dst[e];
            int pos = atomicAdd(&cur[d >> SH], 1);
            words[pos] = src[e] | ((d & (S - 1)) << 24);
        }
    }
}

// ---- k_build: per-bucket {histogram -> scan -> node meta -> sort scatter} ----
__global__ void __launch_bounds__(BLK) k_build(const int* __restrict__ words,
                                               const int* __restrict__ offs,
                                               const float* __restrict__ x,
                                               int* __restrict__ rowstart,
                                               int* __restrict__ cntv,
                                               float* __restrict__ dinv,
                                               float* __restrict__ xd,
                                               int* __restrict__ srcs2,
                                               int n, int NB, int E) {
    __shared__ int cnt[S];
    __shared__ int cur[S];
    int b = blockIdx.x, t = threadIdx.x;
    cnt[t] = 0;
    __syncthreads();
    int e0 = offs[b * G];
    int e1 = (b + 1 < NB) ? offs[(b + 1) * G] : E;
    int bs4 = (e0 + 3) & ~3, be4 = e1 & ~3;

    // phase 1: per-node histogram (1 LDS int atomic / edge, int4-batched)
    if (be4 <= bs4) {
        for (int e = e0 + t; e < e1; e += BLK)
            atomicAdd(&cnt[((unsigned)words[e]) >> 24], 1);
    } else {
        if (t < bs4 - e0) atomicAdd(&cnt[((unsigned)words[e0 + t]) >> 24], 1);
        for (int e = bs4 + 4 * t; e < be4; e += 4 * BLK) {
            int4 w = *reinterpret_cast<const int4*>(words + e);
            atomicAdd(&cnt[((unsigned)w.x) >> 24], 1);
            atomicAdd(&cnt[((unsigned)w.y) >> 24], 1);
            atomicAdd(&cnt[((unsigned)w.z) >> 24], 1);
            atomicAdd(&cnt[((unsigned)w.w) >> 24], 1);
        }
        if (t < e1 - be4) atomicAdd(&cnt[((unsigned)words[be4 + t]) >> 24], 1);
    }
    __syncthreads();

    // phase 2: exclusive scan -> rowstart/cursors; node meta (dinv, xd)
    int c = cnt[t];
    cur[t] = c; __syncthreads();
    for (int off = 1; off < S; off <<= 1) {
        int u = (t >= off) ? cur[t - off] : 0;
        __syncthreads();
        cur[t] += u;
        __syncthreads();
    }
    int pos0 = e0 + cur[t] - c;                    // global CSR row start
    int node = b * S + t;
    rowstart[node] = pos0;
    cntv[node] = c;
    if (node < n) {
        float di = rsqrtf((float)(c + 1));         // +1 self-loop
        dinv[node] = di;
        float4 xv = reinterpret_cast<const float4*>(x)[node];
        float4 o = { xv.x * di, xv.y * di, xv.z * di, xv.w * di };
        reinterpret_cast<float4*>(xd)[node] = o;
    }
    __syncthreads();
    cur[t] = pos0;                                 // absolute cursors
    __syncthreads();

    // phase 3: counting-sort scatter (words re-read is L2-hot; 1 atomic/edge)
    if (be4 <= bs4) {
        for (int e = e0 + t; e < e1; e += BLK) {
            unsigned w = (unsigned)words[e];
            int pos = atomicAdd(&cur[w >> 24], 1);
            srcs2[pos] = w & 0xFFFFFF;
        }
    } else {
        if (t < bs4 - e0) {
            unsigned w = (unsigned)words[e0 + t];
            int pos = atomicAdd(&cur[w >> 24], 1);
            srcs2[pos] = w & 0xFFFFFF;
        }
        for (int e = bs4 + 4 * t; e < be4; e += 4 * BLK) {
            int4 wv = *reinterpret_cast<const int4*>(words + e);
            unsigned w0 = wv.x, w1 = wv.y, w2 = wv.z, w3 = wv.w;
            int p0 = atomicAdd(&cur[w0 >> 24], 1);
            int p1 = atomicAdd(&cur[w1 >> 24], 1);
            int p2 = atomicAdd(&cur[w2 >> 24], 1);
            int p3 = atomicAdd(&cur[w3 >> 24], 1);
            srcs2[p0] = w0 & 0xFFFFFF;
            srcs2[p1] = w1 & 0xFFFFFF;
            srcs2[p2] = w2 & 0xFFFFFF;
            srcs2[p3] = w3 & 0xFFFFFF;
        }
        if (t < e1 - be4) {
            unsigned w = (unsigned)words[be4 + t];
            int pos = atomicAdd(&cur[w >> 24], 1);
            srcs2[pos] = w & 0xFFFFFF;
        }
    }
}

// ---- layer-1: 4 lanes/node register gather-reduce + shfl + fused MLP ----
__global__ void __launch_bounds__(BLK) k_g1(const int* __restrict__ srcs2,
                                            const int* __restrict__ rowstart,
                                            const int* __restrict__ cntv,
                                            const float* __restrict__ dinv,
                                            const float* __restrict__ xd,
                                            const float* __restrict__ W1,
                                            const float* __restrict__ b1,
                                            const float* __restrict__ W2,
                                            float* __restrict__ g2, int n) {
    int gt = blockIdx.x * BLK + threadIdx.x;
    int node = gt >> 2, g = gt & 3;
    if (node >= n) return;
    int rs = rowstart[node], c = cntv[node];
    const float4* feat4 = reinterpret_cast<const float4*>(xd);
    float sx = 0.f, sy = 0.f, sz = 0.f, sw = 0.f;
    int j = g;
    for (; j + 4 < c; j += 8) {                    // 2-way unrolled, stride 4
        int s0 = srcs2[rs + j];
        int s1 = srcs2[rs + j + 4];
        float4 v0 = feat4[s0];
        float4 v1 = feat4[s1];
        sx += v0.x + v1.x; sy += v0.y + v1.y;
        sz += v0.z + v1.z; sw += v0.w + v1.w;
    }
    if (j < c) {
        float4 v = feat4[srcs2[rs + j]];
        sx += v.x; sy += v.y; sz += v.z; sw += v.w;
    }
    // combine the 4 lanes (no atomics, no LDS)
    sx += __shfl_xor(sx, 1); sx += __shfl_xor(sx, 2);
    sy += __shfl_xor(sy, 1); sy += __shfl_xor(sy, 2);
    sz += __shfl_xor(sz, 1); sz += __shfl_xor(sz, 2);
    sw += __shfl_xor(sw, 1); sw += __shfl_xor(sw, 2);
    float4 xv = feat4[node];                       // self-loop term
    sx += xv.x; sy += xv.y; sz += xv.z; sw += xv.w;
    float di = dinv[node];
    float o0 = 0.f, o1 = 0.f, o2 = 0.f, o3 = 0.f;
#pragma unroll
    for (int jj = 0; jj < 16; ++jj) {
        // W1 [4][16] row-major; wave-uniform -> scalar broadcast
        float h = sx * W1[jj] + sy * W1[16 + jj] + sz * W1[32 + jj] + sw * W1[48 + jj];
        float v = di * h + b1[jj];
        v = v > 0.f ? v : 0.f;   // relu
        o0 += v * W2[jj * 4 + 0];
        o1 += v * W2[jj * 4 + 1];
        o2 += v * W2[jj * 4 + 2];
        o3 += v * W2[jj * 4 + 3];
    }
    if (g == 0) {
        float4 o = { o0 * di, o1 * di, o2 * di, o3 * di };
        reinterpret_cast<float4*>(g2)[node] = o;
    }
}

// ---- layer-2: same structure + bias + log_softmax ----
__global__ void __launch_bounds__(BLK) k_g2(const int* __restrict__ srcs2,
                                            const int* __restrict__ rowstart,
                                            const int* __restrict__ cntv,
                                            const float* __restrict__ dinv,
                                            const float* __restrict__ g2v,
                                            const float* __restrict__ b2,
                                            float* __restrict__ out, int n) {
    int gt = blockIdx.x * BLK + threadIdx.x;
    int node = gt >> 2, g = gt & 3;
    if (node >= n) return;
    int rs = rowstart[node], c = cntv[node];
    const float4* feat4 = reinterpret_cast<const float4*>(g2v);
    float sx = 0.f, sy = 0.f, sz = 0.f, sw = 0.f;
    int j = g;
    for (; j + 4 < c; j += 8) {
        int s0 = srcs2[rs + j];
        int s1 = srcs2[rs + j + 4];
        float4 v0 = feat4[s0];
        float4 v1 = feat4[s1];
        sx += v0.x + v1.x; sy += v0.y + v1.y;
        sz += v0.z + v1.z; sw += v0.w + v1.w;
    }
    if (j < c) {
        float4 v = feat4[srcs2[rs + j]];
        sx += v.x; sy += v.y; sz += v.z; sw += v.w;
    }
    sx += __shfl_xor(sx, 1); sx += __shfl_xor(sx, 2);
    sy += __shfl_xor(sy, 1); sy += __shfl_xor(sy, 2);
    sz += __shfl_xor(sz, 1); sz += __shfl_xor(sz, 2);
    sw += __shfl_xor(sw, 1); sw += __shfl_xor(sw, 2);
    float4 gv = feat4[node];                       // self-loop term
    sx += gv.x; sy += gv.y; sz += gv.z; sw += gv.w;
    float di = dinv[node];
    float o0 = di * sx + b2[0];
    float o1 = di * sy + b2[1];
    float o2 = di * sz + b2[2];
    float o3 = di * sw + b2[3];
    float m = fmaxf(fmaxf(o0, o1), fmaxf(o2, o3));
    float sm = expf(o0 - m) + expf(o1 - m) + expf(o2 - m) + expf(o3 - m);
    float l = m + logf(sm);
    if (g == 0) {
        float4 r = { o0 - l, o1 - l, o2 - l, o3 - l };
        reinterpret_cast<float4*>(out)[node] = r;
    }
}

extern "C" void kernel_launch(void* const* d_in, const int* in_sizes, int n_in,
                              void* d_out, int out_size, void* d_ws, size_t ws_size,
                              hipStream_t stream) {
    const float* x  = (const float*)d_in[0];
    const float* W1 = (const float*)d_in[1];
    const float* b1 = (const float*)d_in[2];
    const float* W2 = (const float*)d_in[3];
    const float* b2 = (const float*)d_in[4];
    const int*   ei = (const int*)d_in[5];

    const int n = in_sizes[0] / 4;   // 100000
    const int E = in_sizes[5] / 2;   // 3200000
    const int* src = ei;
    const int* dst = ei + E;

    const int NB    = (n + S - 1) / S;        // 391 buckets
    const int chunk = (E + G - 1) / G;        // 6250 edges/chunk
    const int m     = NB * G;                 // 200192 scan elements
    const int mB    = (m + BLK - 1) / BLK;    // 782 (<= 1024 for scanB)
    const int NS    = NB * S;                 // 100096 padded nodes

    // workspace (16B-aligned, ~31 MB)
    char* ws = (char*)d_ws;
    size_t off = 0;
    int*   words    = (int*)  (ws + off); off += (size_t)E * 4;     // 12.8 MB
    int*   srcs2    = (int*)  (ws + off); off += (size_t)E * 4;     // 12.8 MB
    int*   offs     = (int*)  (ws + off); off += (size_t)m * 4;     // 800 KB
    float* xd       = (float*)(ws + off); off += (size_t)n * 16;    // 1.6 MB
    float* g2       = (float*)(ws + off); off += (size_t)n * 16;    // 1.6 MB
    float* dinv     = (float*)(ws + off); off += (size_t)NS * 4;    // 400 KB
    int*   rowstart = (int*)  (ws + off); off += (size_t)NS * 4;    // 400 KB
    int*   cntv     = (int*)  (ws + off); off += (size_t)NS * 4;    // 400 KB
    int*   bsum     = (int*)  (ws + off); off += 4096;
    int*   boff     = (int*)  (ws + off); off += 4096;
    float* out      = (float*)d_out;

    const int gB = (4 * n + BLK - 1) / BLK;   // 1563 blocks for k_g1/k_g2

    k_binA <<<G,  BLK,  0, stream>>>(dst, offs, E, NB, chunk);
    k_scanA<<<mB, BLK,  0, stream>>>(offs, bsum, m);
    k_scanB<<<1,  1024, 0, stream>>>(bsum, boff, mB);
    k_scanC<<<mB, BLK,  0, stream>>>(offs, boff, m);
    k_binB <<<G,  BLK,  0, stream>>>(src, dst, offs, words, E, NB, chunk);
    k_build<<<NB, BLK,  0, stream>>>(words, offs, x, rowstart, cntv, dinv, xd, srcs2, n, NB, E);
    k_g1   <<<gB, BLK,  0, stream>>>(srcs2, rowstart, cntv, dinv, xd, W1, b1, W2, g2, n);
    k_g2   <<<gB, BLK,  0, stream>>>(srcs2, rowstart, cntv, dinv, g2, b2, out, n);
}